// Round 4
// baseline (980.431 us; speedup 1.0000x reference)
//
#include <hip/hip_runtime.h>
#include <hip/hip_bf16.h>

// Problem constants
#define NTOT 65536      // B*N
#define KNN  20
#define KROW 104        // bf16 kf row stride (67 dims + pad) = 208 bytes

typedef __attribute__((ext_vector_type(4))) float f32x4;
typedef __attribute__((ext_vector_type(8))) short s16x8;

// ws layout (bytes): kfB bf16[65536][104] | normB f32[65536] | nbr i32
#define WS_NORM 13631488
#define WS_NBR  13893632

// ---- k_knn LDS map (bytes) ----
// buf: 96 rows x 257 dwords (256 columns + 1 pad) = 98688
// ring: 4 kq x 4 slots x 3392B (16 keys x 208B + 64B norms) = 54272
#define ROWS 96
#define CSTR 257
#define RING0    98688
#define SLOT_SZ  3392
#define RING_KQ  13568      // 4 slots
#define OFF_TAUG 152960     // unsigned tauG[64]
#define OFF_MG   98688      // mg overlays ring (dead after scan): 64*32*4 = 8192
#define KNN_SMEM 153216
#define THRESH 64           // compact when cntR > THRESH; window 2 groups: 64+32 <= 96

#define WAITV(N) asm volatile("s_waitcnt vmcnt(" #N ")" ::: "memory")
#define BARK do{ __builtin_amdgcn_s_barrier(); asm volatile("" ::: "memory"); }while(0)

__device__ __forceinline__ unsigned short f2bf_rne(float v){
  unsigned u = __float_as_uint(v);
  return (unsigned short)((u + 0x7FFFu + ((u >> 16) & 1u)) >> 16);
}

// ---------------------------------------------------------------------------
// k_prep: kf = [s(16), R^T v(48), pos(3)] -> bf16 rows (stride 104) + f32 norm
// ---------------------------------------------------------------------------
__global__ __launch_bounds__(256) void k_prep(const float* __restrict__ x,
        const float* __restrict__ pos, const float* __restrict__ lfr,
        unsigned short* __restrict__ kfB, float* __restrict__ normB){
  int n = blockIdx.x * 256 + threadIdx.x;
  const float* xr = x + n * 64;
  float R[9];
  #pragma unroll
  for (int j = 0; j < 9; j++) R[j] = lfr[n * 9 + j];
  float c[67];
  #pragma unroll
  for (int i = 0; i < 16; i++) c[i] = xr[i];
  #pragma unroll
  for (int k = 0; k < 16; k++){
    float v0 = xr[16 + 3*k], v1 = xr[17 + 3*k], v2 = xr[18 + 3*k];
    #pragma unroll
    for (int a = 0; a < 3; a++)
      c[16 + 3*k + a] = R[a] * v0 + R[3 + a] * v1 + R[6 + a] * v2;  // R^T v
  }
  #pragma unroll
  for (int a = 0; a < 3; a++) c[64 + a] = pos[n * 3 + a];
  float sq = 0.f;
  #pragma unroll
  for (int d = 0; d < 67; d++) sq += c[d] * c[d];
  __attribute__((aligned(16))) unsigned short row[KROW];
  #pragma unroll
  for (int d = 0; d < 67; d++) row[d] = f2bf_rne(c[d]);
  #pragma unroll
  for (int d = 67; d < KROW; d++) row[d] = 0;
  uint4* dst = (uint4*)(kfB + (size_t)n * KROW);
  const uint4* s4 = (const uint4*)row;
  #pragma unroll
  for (int i = 0; i < 13; i++) dst[i] = s4[i];
  normB[n] = sq;
}

// ---------------------------------------------------------------------------
// col_compact: exact top-32 (unique 32-bit packed values) of one column with
// cn (<=96) entries. 32-round ballot binary search for the 32nd smallest,
// then ballot-prefix rewrite. Wave-local, no barriers.
// ---------------------------------------------------------------------------
__device__ __forceinline__ unsigned col_compact(unsigned* buf,
    int col, int cn, int lane){
  unsigned e0 = (lane < cn) ? buf[lane * CSTR + col] : 0xFFFFFFFFu;
  unsigned e1 = (lane + 64 < cn) ? buf[(lane + 64) * CSTR + col] : 0xFFFFFFFFu;
  unsigned T = 0;
  #pragma unroll 1
  for (int b = 31; b >= 0; --b){
    unsigned cand = T | (1u << b);
    int c = __popcll(__ballot(e0 < cand)) + __popcll(__ballot(e1 < cand));
    if (c <= 31) T = cand;   // largest U with count(<U)<=31  ==> 32nd smallest
  }
  unsigned long long m0 = __ballot(e0 <= T);
  unsigned long long m1 = __ballot(e1 <= T);
  int b1 = __popcll(m0);
  unsigned long long ltm = (1ull << lane) - 1ull;
  if (e0 <= T) buf[__popcll(m0 & ltm) * CSTR + col] = e0;
  if (e1 <= T) buf[(b1 + __popcll(m1 & ltm)) * CSTR + col] = e1;
  return T;
}

// ---------------------------------------------------------------------------
// k_knn: 256 blocks x 1024 thr (16 waves). Wave (wq,kq): 16 queries x 4096
// keys (quarter kq). Keys staged into a shared per-kq LDS ring (4 slots x 16
// keys) by producer wave wq=0 of each kq via global_load_lds issued 3 groups
// ahead; counted s_waitcnt vmcnt(10) + one raw s_barrier per group (no
// drains). Candidate counts in quad-uniform registers; tau via atomicMin.
// ---------------------------------------------------------------------------
__global__ __launch_bounds__(1024, 4) void k_knn(
    const unsigned short* __restrict__ kfB, const float* __restrict__ normB,
    const float* __restrict__ x, const float* __restrict__ pos,
    const float* __restrict__ lfr, int* __restrict__ nbr){
  __shared__ __attribute__((aligned(16))) char smem[KNN_SMEM];
  unsigned* buf = (unsigned*)smem;
  unsigned* tauG = (unsigned*)(smem + OFF_TAUG);
  unsigned* mg = (unsigned*)(smem + OFF_MG);

  int tid = threadIdx.x;
  int blk = blockIdx.x;
  int b = blk & 3;                 // batch; XCD (blk%8) serves one batch slice
  int qloc0 = (blk >> 2) << 6;     // query block within batch: 0..4032
  int bbase = b << 14;

  if (tid < 64) tauG[tid] = 0x7F7FC000u;   // huge float (not NaN)

  int lane = tid & 63;
  int wv = tid >> 6;               // 0..15
  int wq = wv >> 2;                // query sub-group 0..3
  int kq = wv & 3;                 // key quarter 0..3
  int l15 = lane & 15, quad = lane >> 4;
  int colB = (wq << 6) + kq;       // col = colB + quad*16 + r*4

  // A fragments: wave's 16 queries
  int qloc = qloc0 + (wq << 4);
  s16x8 af[3];
  {
    int nodeA = bbase + ((qloc + l15) << 2);
    const unsigned short* ap = kfB + (size_t)nodeA * KROW + quad * 8;
    af[0] = *(const s16x8*)(ap);
    af[1] = *(const s16x8*)(ap + 32);
    af[2] = *(const s16x8*)(ap + 64);
  }
  float qsq[4];
  #pragma unroll
  for (int r = 0; r < 4; r++)
    qsq[r] = normB[bbase + ((qloc + (quad << 2) + r) << 2)];

  float tauR[4] = {3.0e38f, 3.0e38f, 3.0e38f, 3.0e38f};
  int cntR[4] = {32, 32, 32, 32};  // seeds occupy rows 0..31

  // ring bases: consumers read kq's ring; producers (wv<4) fill ring wv
  char* myring = smem + RING0 + kq * RING_KQ;
  char* prodring = smem + RING0 + wv * RING_KQ;
  const char* gkey = (const char*)(kfB + (size_t)(bbase + (wv << 12)) * KROW);
  const char* gnrm = (const char*)(normB + bbase + (wv << 12));

  // per-lane DMA chunk constants: chunk c covers bytes [c*16, c*16+16) of the
  // 16x208B key block; c = row*13 + off  (208 = 13*16)
  int rowc[3], offc[3];
  #pragma unroll
  for (int t = 0; t < 3; t++){
    int c = t * 64 + lane;
    rowc[t] = c / 13; offc[t] = c - 13 * rowc[t];
  }
  int row3 = 0, off3 = 0;
  {
    int c = 192 + (lane & 15);
    row3 = c / 13; off3 = c - 13 * row3;
  }

  auto issue_dma = [&](int g){
    char* dst = prodring + (g & 3) * SLOT_SZ;
    const char* src = gkey + (size_t)g * 3328;   // 16 rows x 208B
    #pragma unroll
    for (int t = 0; t < 3; t++)
      __builtin_amdgcn_global_load_lds(
          (const __attribute__((address_space(1))) void*)(src + rowc[t] * 208 + (offc[t] << 4)),
          (__attribute__((address_space(3))) void*)(dst + t * 1024 + lane * 16), 16, 0, 0);
    if (lane < 16)
      __builtin_amdgcn_global_load_lds(
          (const __attribute__((address_space(1))) void*)(src + row3 * 208 + (off3 << 4)),
          (__attribute__((address_space(3))) void*)(dst + 3072 + lane * 16), 16, 0, 0);
    if (lane < 4)
      __builtin_amdgcn_global_load_lds(
          (const __attribute__((address_space(1))) void*)(gnrm + (size_t)g * 64 + lane * 16),
          (__attribute__((address_space(3))) void*)(dst + 3328 + lane * 16), 16, 0, 0);
  };

  auto comp = [&](const s16x8 bf[3], float ksqv, float d2v[4]){
    f32x4 acc = (f32x4){0.f, 0.f, 0.f, 0.f};
    acc = __builtin_amdgcn_mfma_f32_16x16x32_bf16(af[0], bf[0], acc, 0, 0, 0);
    acc = __builtin_amdgcn_mfma_f32_16x16x32_bf16(af[1], bf[1], acc, 0, 0, 0);
    acc = __builtin_amdgcn_mfma_f32_16x16x32_bf16(af[2], bf[2], acc, 0, 0, 0);
    #pragma unroll
    for (int r = 0; r < 4; r++)
      d2v[r] = fmaxf(qsq[r] + ksqv - 2.f * acc[r], 0.f);
  };

  auto seed = [&](const float d2v[4], int g){
    int kidx = (kq << 12) + (g << 4) + l15;
    #pragma unroll
    for (int r = 0; r < 4; r++){
      unsigned pk = ((__float_as_uint(d2v[r]) + 0x2000u) & 0xFFFFC000u) | (unsigned)kidx;
      buf[((g << 4) + l15) * CSTR + colB + (quad << 4) + (r << 2)] = pk;
    }
  };

  auto process = [&](const float d2v[4], int g){
    bool p[4];
    #pragma unroll
    for (int r = 0; r < 4; r++) p[r] = d2v[r] < tauR[r];
    if (__any(p[0] | p[1] | p[2] | p[3])){
      int kidx = (kq << 12) + (g << 4) + l15;
      #pragma unroll
      for (int r = 0; r < 4; r++){
        unsigned long long m = __ballot(p[r]);
        if (m){
          int lo = (int)((m >> (quad << 4)) & 0xFFFFull);
          if (lo){
            int colr = colB + (quad << 4) + (r << 2);
            int pre = __popc(lo & ((1 << l15) - 1));
            if (p[r]){
              unsigned pk = ((__float_as_uint(d2v[r]) + 0x2000u) & 0xFFFFC000u) | (unsigned)kidx;
              buf[(cntR[r] + pre) * CSTR + colr] = pk;
            }
            cntR[r] += __popc(lo);      // quad-uniform update, no atomics
          }
        }
      }
    }
  };

  auto check_compact = [&](int limit){
    #pragma unroll
    for (int r = 0; r < 4; r++){
      unsigned long long mr = __ballot(cntR[r] > limit);
      while (mr){
        int ldr = __ffsll((unsigned long long)mr) - 1;
        int qd = ldr >> 4;
        mr &= ~(0xFFFFull << (qd << 4));
        int col = colB + (qd << 4) + (r << 2);
        int cn = __shfl(cntR[r], qd << 4, 64);
        unsigned T = col_compact(buf, col, cn, lane);
        if (quad == qd) cntR[r] = 32;
        if (lane == 0) atomicMin(&tauG[(wq << 4) + (qd << 2) + r], T);
      }
    }
  };

  auto body = [&](int g){
    if ((wv < 4) && (g <= 252)) issue_dma(g + 3);
    const char* src = myring + (g & 3) * SLOT_SZ;
    const char* kr = src + l15 * 208 + quad * 16;
    s16x8 bf[3];
    bf[0] = *(const s16x8*)(kr);
    bf[1] = *(const s16x8*)(kr + 64);
    bf[2] = *(const s16x8*)(kr + 128);
    float kn = *(const float*)(src + 3328 + (l15 << 2));
    float d2v[4];
    comp(bf, kn, d2v);
    if (g < 2) seed(d2v, g);
    else process(d2v, g);
    if (g & 1){
      check_compact(THRESH);
      uint4 tg = *(const uint4*)&tauG[(wq << 4) + (quad << 2)];
      tauR[0] = __uint_as_float(tg.x & 0xFFFFC000u);
      tauR[1] = __uint_as_float(tg.y & 0xFFFFC000u);
      tauR[2] = __uint_as_float(tg.z & 0xFFFFC000u);
      tauR[3] = __uint_as_float(tg.w & 0xFFFFC000u);
    }
  };

  // ---- prologue: producers fill slots 0..2; full drain once ----
  if (wv < 4){ issue_dma(0); issue_dma(1); issue_dma(2); }
  __syncthreads();   // slots 0..2 landed; tauG init visible

  // ---- main scan: one raw barrier per group, counted vmcnt, no drains ----
  // invariant at group g (g>=3): producer outstanding = slots {g,g+1,g+2}
  // = 15 loads; vmcnt(10) lands slot g (in-order completion).
  #pragma unroll 1
  for (int g = 0; g < 254; ++g){
    WAITV(10); BARK;
    body(g);
  }
  WAITV(5);  BARK; body(254);
  WAITV(0);  BARK; body(255);

  // ---- final per-column exact top-32 (all columns end at exactly 32) ----
  check_compact(32);
  __syncthreads();

  // ---- per-query merge of 4 columns (4x32 = 128 fixed) -> top-32 into mg ----
  #pragma unroll 1
  for (int s = 0; s < 4; s++){
    int q = (wv << 2) + s;           // 0..63
    unsigned e0 = buf[(lane & 31) * CSTR + (q << 2) + (lane >> 5)];
    unsigned e1 = buf[(lane & 31) * CSTR + (q << 2) + 2 + (lane >> 5)];
    unsigned T = 0;
    #pragma unroll 1
    for (int bb = 31; bb >= 0; --bb){
      unsigned cand = T | (1u << bb);
      int c = __popcll(__ballot(e0 < cand)) + __popcll(__ballot(e1 < cand));
      if (c <= 31) T = cand;
    }
    unsigned long long m0 = __ballot(e0 <= T);
    unsigned long long m1 = __ballot(e1 <= T);
    int b1 = __popcll(m0);
    unsigned long long ltm = (1ull << lane) - 1ull;
    int p0 = __popcll(m0 & ltm);
    int p1 = b1 + __popcll(m1 & ltm);
    if ((e0 <= T) && (p0 < 32)) mg[(q << 5) + p0] = e0;
    if ((e1 <= T) && (p1 < 32)) mg[(q << 5) + p1] = e1;
  }
  __syncthreads();

  // ---- fp64 exact rerank of 32 candidates/query (overlays buf region) ----
  double* qkf = (double*)(smem);
  double* rrD = (double*)(smem + 34304);
  int*    rrI = (int*)(smem + 50688);

  {
    int t16 = tid & 15, q = tid >> 4;
    int node = bbase + ((qloc0 + q) << 2);
    const float* xr = x + node * 64;
    for (int dd = t16; dd < 67; dd += 16){
      double val;
      if (dd < 16) val = (double)xr[dd];
      else if (dd < 64){
        int r = dd - 16; int k = r / 3; int a = r - 3 * k;
        val = (double)lfr[node*9 + a]     * (double)xr[16 + 3*k]
            + (double)lfr[node*9 + 3 + a] * (double)xr[17 + 3*k]
            + (double)lfr[node*9 + 6 + a] * (double)xr[18 + 3*k];
      } else val = (double)pos[node*3 + (dd - 64)];
      qkf[q * 67 + dd] = val;
    }
  }
  __syncthreads();
  {
    int t16 = tid & 15, q = tid >> 4;
    for (int j = t16; j < 32; j += 16){
      int idx = (int)(mg[(q << 5) + j] & 0x3FFFu);
      int node = bbase + idx;
      const float* xr = x + node * 64;
      double R[9];
      #pragma unroll
      for (int t = 0; t < 9; t++) R[t] = (double)lfr[node * 9 + t];
      double d2 = 0.0;
      #pragma unroll
      for (int dd = 0; dd < 16; dd++){ double t = (double)xr[dd] - qkf[q*67 + dd]; d2 += t * t; }
      #pragma unroll
      for (int k = 0; k < 16; k++){
        double v0 = xr[16 + 3*k], v1 = xr[17 + 3*k], v2 = xr[18 + 3*k];
        #pragma unroll
        for (int a = 0; a < 3; a++){
          double val = R[a] * v0 + R[3 + a] * v1 + R[6 + a] * v2;
          double t = val - qkf[q*67 + 16 + 3*k + a]; d2 += t * t;
        }
      }
      #pragma unroll
      for (int a = 0; a < 3; a++){ double t = (double)pos[node*3 + a] - qkf[q*67 + 64 + a]; d2 += t * t; }
      rrD[q * 32 + j] = d2; rrI[q * 32 + j] = idx;
    }
  }
  __syncthreads();
  if (tid < 64){
    int qq = tid;
    int qid = (b << 12) + qloc0 + qq;
    #pragma unroll 1
    for (int s = 0; s < KNN; s++){
      double best = rrD[qq * 32 + s]; int bi = s;
      for (int t = s + 1; t < 32; t++){
        double v = rrD[qq * 32 + t]; if (v < best){ best = v; bi = t; }
      }
      double tv = rrD[qq * 32 + bi]; rrD[qq * 32 + bi] = rrD[qq * 32 + s]; rrD[qq * 32 + s] = tv;
      int ti = rrI[qq * 32 + bi]; rrI[qq * 32 + bi] = rrI[qq * 32 + s]; rrI[qq * 32 + s] = ti;
      nbr[qid * KNN + s] = bbase + rrI[qq * 32 + s];
    }
  }
}

// ---------------------------------------------------------------------------
// k_mlp (MFMA rewrite): 8 queries/block = 160 edge-rows (10 m-tiles), 512 thr
// (8 waves, wave wv owns 16 output cols). bf16 MFMA both layers, fp32 acc.
// LDS k-blocked layouts [k/32][row][32] (16B-aligned b128 frags, 2-way banks).
// Max-over-20-edges fully in registers via compile-time query-boundary masks.
// ---------------------------------------------------------------------------
#define M_X   0         // xs f32[160][68] = 43520 ; later Wt2 bf16[4][128][32]
#define M_H   43520     // hB bf16[4][160][32] = 40960
#define M_A1  84480     // a1B bf16[4][160][32] = 40960 (early: nbrL/xdL/lfL overlay)
#define M_W   125440    // Wt1 bf16[4][128][32] = 32768
#define M_B1  158208    // b1 f32[128]
#define M_B2  158720    // b2 f32[128]
#define M_SZ  159232

__global__ __launch_bounds__(512) void k_mlp(const float* __restrict__ x,
    const float* __restrict__ lfr, const int* __restrict__ nbr,
    const float* __restrict__ W1, const float* __restrict__ b1,
    const float* __restrict__ W2, const float* __restrict__ b2,
    float* __restrict__ out){
  __shared__ __attribute__((aligned(16))) char smem[M_SZ];
  float* xsF = (float*)(smem + M_X);
  unsigned short* hB = (unsigned short*)(smem + M_H);
  unsigned short* a1B = (unsigned short*)(smem + M_A1);
  unsigned short* wt1 = (unsigned short*)(smem + M_W);
  unsigned short* wt2 = (unsigned short*)(smem + M_X);
  float* b1L = (float*)(smem + M_B1);
  float* b2L = (float*)(smem + M_B2);
  int*   nbrL = (int*)(smem + M_A1);            // overlay (dead before a1 writes)
  float* xdL  = (float*)(smem + M_A1 + 640);    // 8x64 f32
  float* lfL  = (float*)(smem + M_A1 + 2688);   // 8x9 f32

  int tid = threadIdx.x;
  int qid0 = blockIdx.x * 8;
  int lane = tid & 63, wv = tid >> 6;
  int l15 = lane & 15, quad = lane >> 4;

  // ---- init loads ----
  if (tid < 160) nbrL[tid] = nbr[qid0 * 20 + tid];
  {
    int q = tid >> 6, d = tid & 63;
    int qid = qid0 + q;
    int node = ((qid >> 12) << 14) + ((qid & 4095) << 2);
    xdL[q * 64 + d] = x[node * 64 + d];
  }
  if (tid < 72){
    int q = tid / 9, j = tid - 9 * q;
    int qid = qid0 + q;
    int node = ((qid >> 12) << 14) + ((qid & 4095) << 2);
    lfL[q * 9 + j] = lfr[node * 9 + j];
  }
  if (tid < 128){ b1L[tid] = b1[tid]; b2L[tid] = b2[tid]; }
  __syncthreads();

  // ---- gather x_src into xs (160 rows x 64 f32, stride 68) ----
  {
    int f4 = tid & 15;
    #pragma unroll
    for (int p = 0; p < 5; p++){
      int e = (tid >> 4) + (p << 5);
      float4 v = *(const float4*)&x[(size_t)nbrL[e] * 64 + (f4 << 2)];
      *(float4*)&xsF[e * 68 + (f4 << 2)] = v;
    }
  }
  __syncthreads();

  // ---- build h bf16 into hB [d>>5][e][d&31] ----
  {
    int d = tid & 127, eo = tid >> 7;   // eo 0..3
    int cls, kk = 0, aa = 0;
    if (d < 64) cls = 0;
    else { int dd = d - 64;
      if (dd < 16) cls = 1;
      else { cls = 2; int r = dd - 16; kk = (r * 21846) >> 16; aa = r - 3 * kk; } }
    int hoff = ((d >> 5) * 160) * 32 + (d & 31);
    #pragma unroll 4
    for (int p = 0; p < 40; p++){
      int e = eo + (p << 2);
      int q = (e * 3277) >> 16;       // e/20 for e<160
      float v;
      if (cls == 0) v = xdL[q * 64 + d];
      else if (cls == 1) v = xsF[e * 68 + (d - 64)] - xdL[q * 64 + (d - 64)];
      else {
        int base = 16 + 3 * kk;
        float u0 = xsF[e * 68 + base]     - xdL[q * 64 + base];
        float u1 = xsF[e * 68 + base + 1] - xdL[q * 64 + base + 1];
        float u2 = xsF[e * 68 + base + 2] - xdL[q * 64 + base + 2];
        v = lfL[q * 9 + aa * 3] * u0 + lfL[q * 9 + aa * 3 + 1] * u1 + lfL[q * 9 + aa * 3 + 2] * u2;
      }
      hB[hoff + e * 32] = f2bf_rne(v);
    }
  }
  __syncthreads();   // hB done; xs/xdL/lfL/nbrL dead

  // ---- stage Wt1 -> M_W, Wt2 -> M_X  (layout [k>>5][n][32], value W[k][n]) ----
  #pragma unroll 4
  for (int i = tid; i < 16384; i += 512){
    int k = i >> 7, n = i & 127;
    int a = ((k >> 5) * 128 + n) * 32 + (k & 31);
    wt1[a] = f2bf_rne(W1[i]);
    wt2[a] = f2bf_rne(W2[i]);
  }
  __syncthreads();   // weights visible

  // ---- layer 1: a1 = relu(h @ W1 + b1) ----
  {
    s16x8 bfr[4];
    #pragma unroll
    for (int ks = 0; ks < 4; ks++)
      bfr[ks] = *(const s16x8*)(wt1 + ((ks * 128 + (wv << 4) + l15) * 32 + (quad << 3)));
    float b1v = b1L[(wv << 4) + l15];
    int colhi = wv >> 1, collo = ((wv & 1) << 4) + l15;
    #pragma unroll
    for (int mt = 0; mt < 10; mt++){
      f32x4 acc = (f32x4){0.f, 0.f, 0.f, 0.f};
      #pragma unroll
      for (int ks = 0; ks < 4; ks++){
        s16x8 af = *(const s16x8*)(hB + ((ks * 160 + (mt << 4) + l15) * 32 + (quad << 3)));
        acc = __builtin_amdgcn_mfma_f32_16x16x32_bf16(af, bfr[ks], acc, 0, 0, 0);
      }
      #pragma unroll
      for (int r = 0; r < 4; r++){
        float v = fmaxf(acc[r] + b1v, 0.f);
        int row = (mt << 4) + (quad << 2) + r;
        a1B[(colhi * 160 + row) * 32 + collo] = f2bf_rne(v);
      }
    }
  }
  __syncthreads();   // a1 complete

  // ---- layer 2 + max over edges (registers only) ----
  {
    s16x8 bfr[4];
    #pragma unroll
    for (int ks = 0; ks < 4; ks++)
      bfr[ks] = *(const s16x8*)(wt2 + ((ks * 128 + (wv << 4) + l15) * 32 + (quad << 3)));
    float mxv[8];
    #pragma unroll
    for (int q = 0; q < 8; q++) mxv[q] = -3.0e38f;
    const int QA[10]  = {0,0,1,2,3,4,4,5,6,7};
    const int CUT[10] = {16,4,8,12,16,16,4,8,12,16};
    #pragma unroll
    for (int mt = 0; mt < 10; mt++){
      f32x4 acc = (f32x4){0.f, 0.f, 0.f, 0.f};
      #pragma unroll
      for (int ks = 0; ks < 4; ks++){
        s16x8 af = *(const s16x8*)(a1B + ((ks * 160 + (mt << 4) + l15) * 32 + (quad << 3)));
        acc = __builtin_amdgcn_mfma_f32_16x16x32_bf16(af, bfr[ks], acc, 0, 0, 0);
      }
      int qa = QA[mt], cut = CUT[mt];
      if (cut >= 16){
        #pragma unroll
        for (int r = 0; r < 4; r++) mxv[qa] = fmaxf(mxv[qa], acc[r]);
      } else {
        #pragma unroll
        for (int r = 0; r < 4; r++){
          int lr = (quad << 2) + r;
          bool toA = lr < cut;
          mxv[qa]     = fmaxf(mxv[qa],     toA ? acc[r] : -3.0e38f);
          mxv[qa + 1] = fmaxf(mxv[qa + 1], toA ? -3.0e38f : acc[r]);
        }
      }
    }
    // combine across quads (rows) -- all lanes end with full per-col max
    #pragma unroll
    for (int q = 0; q < 8; q++){
      float v = mxv[q];
      v = fmaxf(v, __shfl_xor(v, 16, 64));
      v = fmaxf(v, __shfl_xor(v, 32, 64));
      mxv[q] = v;
    }
    if (quad == 0){
      int col = (wv << 4) + l15;
      float b2v = b2L[col];
      #pragma unroll
      for (int q = 0; q < 8; q++)
        out[(size_t)(qid0 + q) * 128 + col] = mxv[q] + b2v;
    }
  }
}

// ---------------------------------------------------------------------------
// k_tail: pos[idx], batch[idx], lframes[idx] as fp32 at flat offsets.
// ---------------------------------------------------------------------------
__global__ __launch_bounds__(256) void k_tail(const float* __restrict__ pos,
    const float* __restrict__ lfr, float* __restrict__ out){
  int q = blockIdx.x * 256 + threadIdx.x;   // 0..16383
  int b = q >> 12;
  int node = (b << 14) + ((q & 4095) << 2);
  float* o_pos = out + 2097152;    // 16384*128
  float* o_bat = out + 2146304;    // + 16384*3
  float* o_lf  = out + 2162688;    // + 16384
  #pragma unroll
  for (int j = 0; j < 3; j++) o_pos[q * 3 + j] = pos[node * 3 + j];
  o_bat[q] = (float)b;
  #pragma unroll
  for (int j = 0; j < 9; j++) o_lf[q * 9 + j] = lfr[node * 9 + j];
}

extern "C" void kernel_launch(void* const* d_in, const int* in_sizes, int n_in,
                              void* d_out, int out_size, void* d_ws, size_t ws_size,
                              hipStream_t stream){
  const float* x   = (const float*)d_in[0];
  const float* pos = (const float*)d_in[1];
  const float* lfr = (const float*)d_in[2];
  // d_in[3] = batch (recomputed analytically)
  const float* W1  = (const float*)d_in[4];
  const float* b1  = (const float*)d_in[5];
  const float* W2  = (const float*)d_in[6];
  const float* b2  = (const float*)d_in[7];

  unsigned short* kfB = (unsigned short*)d_ws;
  float* normB = (float*)((char*)d_ws + WS_NORM);
  int*   nbr   = (int*)((char*)d_ws + WS_NBR);
  float* out = (float*)d_out;

  hipLaunchKernelGGL(k_prep, dim3(256),  dim3(256),  0, stream, x, pos, lfr, kfB, normB);
  hipLaunchKernelGGL(k_knn,  dim3(256),  dim3(1024), 0, stream, kfB, normB, x, pos, lfr, nbr);
  hipLaunchKernelGGL(k_mlp,  dim3(2048), dim3(512),  0, stream, x, lfr, nbr, W1, b1, W2, b2, out);
  hipLaunchKernelGGL(k_tail, dim3(64),   dim3(256),  0, stream, pos, lfr, out);
}

// Round 5
// 681.627 us; speedup vs baseline: 1.4384x; 1.4384x over previous
//
#include <hip/hip_runtime.h>
#include <hip/hip_bf16.h>

// Problem constants
#define NTOT 65536      // B*N
#define KNN  20
#define KROW 104        // bf16 kf row stride (67 dims + pad) = 208 bytes

typedef __attribute__((ext_vector_type(4))) float f32x4;
typedef __attribute__((ext_vector_type(8))) short s16x8;

// ws layout (bytes): kfB bf16[65536][104] | normB f32[65536] | nbr i32
#define WS_NORM 13631488
#define WS_NBR  13893632

// ---- k_knn LDS map (bytes) ----
// buf: 96 rows x 257 dwords (256 columns + 1 pad for bank spread) = 98688
// col = qLocal*4 + kq   (qLocal 0..63 within block, kq = key quarter 0..3)
#define ROWS 96
#define CSTR 257
#define OFF_MG   98688      // unsigned mg[64*32] = 8192
#define OFF_TAUG 106880     // unsigned tauG[64]
#define KNN_SMEM 107136
#define THRESH 64           // compact when cntR > THRESH; check every 2 groups: 64+32 <= 96

#define WAITV(N) asm volatile("s_waitcnt vmcnt(" #N ")" ::: "memory")
// volatile asm loads: cannot be sunk by the scheduler -> real prefetch distance
#define GLD0(dst, ap)   asm volatile("global_load_dwordx4 %0, %1, off"            : "=v"(dst) : "v"(ap))
#define GLD64(dst, ap)  asm volatile("global_load_dwordx4 %0, %1, off offset:64"  : "=v"(dst) : "v"(ap))
#define GLD128(dst, ap) asm volatile("global_load_dwordx4 %0, %1, off offset:128" : "=v"(dst) : "v"(ap))

__device__ __forceinline__ unsigned short f2bf_rne(float v){
  unsigned u = __float_as_uint(v);
  return (unsigned short)((u + 0x7FFFu + ((u >> 16) & 1u)) >> 16);
}

// ---------------------------------------------------------------------------
// k_prep: kf = [s(16), R^T v(48), pos(3), -0.5|k|^2 as bf16 hi/lo] -> bf16
// rows (stride 104) + f32 norm. Dims 67/68 carry the norm so the d2 MFMA
// needs no separate ksq load (query side patches 1.0 into those dims).
// ---------------------------------------------------------------------------
__global__ __launch_bounds__(256) void k_prep(const float* __restrict__ x,
        const float* __restrict__ pos, const float* __restrict__ lfr,
        unsigned short* __restrict__ kfB, float* __restrict__ normB){
  int n = blockIdx.x * 256 + threadIdx.x;
  const float* xr = x + n * 64;
  float R[9];
  #pragma unroll
  for (int j = 0; j < 9; j++) R[j] = lfr[n * 9 + j];
  float c[67];
  #pragma unroll
  for (int i = 0; i < 16; i++) c[i] = xr[i];
  #pragma unroll
  for (int k = 0; k < 16; k++){
    float v0 = xr[16 + 3*k], v1 = xr[17 + 3*k], v2 = xr[18 + 3*k];
    #pragma unroll
    for (int a = 0; a < 3; a++)
      c[16 + 3*k + a] = R[a] * v0 + R[3 + a] * v1 + R[6 + a] * v2;  // R^T v
  }
  #pragma unroll
  for (int a = 0; a < 3; a++) c[64 + a] = pos[n * 3 + a];
  float sq = 0.f;
  #pragma unroll
  for (int d = 0; d < 67; d++) sq += c[d] * c[d];
  __attribute__((aligned(16))) unsigned short row[KROW];
  #pragma unroll
  for (int d = 0; d < 67; d++) row[d] = f2bf_rne(c[d]);
  #pragma unroll
  for (int d = 67; d < KROW; d++) row[d] = 0;
  // -0.5*|k|^2 split into bf16 hi/lo at dims 67,68
  {
    float h = -0.5f * sq;
    unsigned short hi = f2bf_rne(h);
    float hif = __uint_as_float(((unsigned)hi) << 16);
    row[67] = hi;
    row[68] = f2bf_rne(h - hif);
  }
  uint4* dst = (uint4*)(kfB + (size_t)n * KROW);
  const uint4* s4 = (const uint4*)row;
  #pragma unroll
  for (int i = 0; i < 13; i++) dst[i] = s4[i];
  normB[n] = sq;
}

// ---------------------------------------------------------------------------
// col_compact: exact top-32 (unique 32-bit packed values) of one column with
// cn (<=96) entries. 32-round ballot binary search for the 32nd smallest,
// then ballot-prefix rewrite. Wave-local, no barriers.
// ---------------------------------------------------------------------------
__device__ __forceinline__ unsigned col_compact(unsigned* buf,
    int col, int cn, int lane){
  unsigned e0 = (lane < cn) ? buf[lane * CSTR + col] : 0xFFFFFFFFu;
  unsigned e1 = (lane + 64 < cn) ? buf[(lane + 64) * CSTR + col] : 0xFFFFFFFFu;
  unsigned T = 0;
  #pragma unroll 1
  for (int b = 31; b >= 0; --b){
    unsigned cand = T | (1u << b);
    int c = __popcll(__ballot(e0 < cand)) + __popcll(__ballot(e1 < cand));
    if (c <= 31) T = cand;   // largest U with count(<U)<=31  ==> 32nd smallest
  }
  unsigned long long m0 = __ballot(e0 <= T);
  unsigned long long m1 = __ballot(e1 <= T);
  int b1 = __popcll(m0);
  unsigned long long ltm = (1ull << lane) - 1ull;
  if (e0 <= T) buf[__popcll(m0 & ltm) * CSTR + col] = e0;
  if (e1 <= T) buf[(b1 + __popcll(m1 & ltm)) * CSTR + col] = e1;
  return T;
}

// ---------------------------------------------------------------------------
// k_knn: barrier-free scan (R3 structure). 256 blocks x 1024 thr (16 waves).
// Wave (wq,kq): 16 queries x 4096 keys. Keys direct from global, 4-deep
// REGISTER pipeline via volatile-asm global_load_dwordx4 + counted
// s_waitcnt vmcnt(9) + sched_barrier(0) (compiler cannot sink the loads).
// Candidate counts in quad-uniform registers; shared monotone tau(atomicMin).
// ---------------------------------------------------------------------------
__global__ __launch_bounds__(1024, 4) void k_knn(
    const unsigned short* __restrict__ kfB, const float* __restrict__ normB,
    const float* __restrict__ x, const float* __restrict__ pos,
    const float* __restrict__ lfr, int* __restrict__ nbr){
  __shared__ __attribute__((aligned(16))) char smem[KNN_SMEM];
  unsigned* buf = (unsigned*)smem;
  unsigned* mg = (unsigned*)(smem + OFF_MG);
  unsigned* tauG = (unsigned*)(smem + OFF_TAUG);

  int tid = threadIdx.x;
  int blk = blockIdx.x;
  int b = blk & 3;                 // batch; XCD (blk%8) serves one batch slice
  int qloc0 = (blk >> 2) << 6;     // query block within batch: 0..4032
  int bbase = b << 14;

  if (tid < 64) tauG[tid] = 0x7F7FC000u;   // huge float (not NaN)

  int lane = tid & 63;
  int wv = tid >> 6;               // 0..15
  int wq = wv >> 2;                // query sub-group 0..3
  int kq = wv & 3;                 // key quarter 0..3
  int l15 = lane & 15, quad = lane >> 4;
  int colB = (wq << 6) + kq;       // col = colB + quad*16 + r*4

  // A fragments: wave's 16 queries; patch dims 67/68 -> 1.0 (norm-fold trick)
  int qloc = qloc0 + (wq << 4);
  s16x8 af[3];
  {
    int nodeA = bbase + ((qloc + l15) << 2);
    const unsigned short* ap = kfB + (size_t)nodeA * KROW + quad * 8;
    af[0] = *(const s16x8*)(ap);
    af[1] = *(const s16x8*)(ap + 32);
    af[2] = *(const s16x8*)(ap + 64);
  }
  if (quad == 0){ af[2][3] = (short)0x3F80; af[2][4] = (short)0x3F80; }
  float qsq[4];
  #pragma unroll
  for (int r = 0; r < 4; r++)
    qsq[r] = normB[bbase + ((qloc + (quad << 2) + r) << 2)];

  float tauR[4] = {3.0e38f, 3.0e38f, 3.0e38f, 3.0e38f};
  int cntR[4] = {32, 32, 32, 32};  // seeds occupy rows 0..31

  // per-lane key stream base: key (kq*4096 + g*16 + l15), bytes quad*16..+48
  const char* kcur = (const char*)kfB
      + (size_t)(bbase + (kq << 12) + l15) * 208 + quad * 16;

  __syncthreads();   // tauG init visible

  s16x8 sl[4][3];    // 4-slot register pipeline (48 VGPRs, asm-pinned)

  auto comp = [&](const s16x8 bf[3], float d2v[4]){
    f32x4 acc = (f32x4){0.f, 0.f, 0.f, 0.f};
    acc = __builtin_amdgcn_mfma_f32_16x16x32_bf16(af[0], bf[0], acc, 0, 0, 0);
    acc = __builtin_amdgcn_mfma_f32_16x16x32_bf16(af[1], bf[1], acc, 0, 0, 0);
    acc = __builtin_amdgcn_mfma_f32_16x16x32_bf16(af[2], bf[2], acc, 0, 0, 0);
    #pragma unroll
    for (int r = 0; r < 4; r++)                      // d2 = |q|^2 - 2*acc
      d2v[r] = fmaxf(fmaf(-2.f, acc[r], qsq[r]), 0.f);
  };

  auto seed = [&](const float d2v[4], int g){
    int kidx = (kq << 12) + (g << 4) + l15;
    #pragma unroll
    for (int r = 0; r < 4; r++){
      unsigned pk = ((__float_as_uint(d2v[r]) + 0x2000u) & 0xFFFFC000u) | (unsigned)kidx;
      buf[((g << 4) + l15) * CSTR + colB + (quad << 4) + (r << 2)] = pk;
    }
  };

  auto process = [&](const float d2v[4], int g){
    bool p[4];
    #pragma unroll
    for (int r = 0; r < 4; r++) p[r] = d2v[r] < tauR[r];
    if (__any(p[0] | p[1] | p[2] | p[3])){
      int kidx = (kq << 12) + (g << 4) + l15;
      #pragma unroll
      for (int r = 0; r < 4; r++){
        unsigned long long m = __ballot(p[r]);
        if (m){
          int lo = (int)((m >> (quad << 4)) & 0xFFFFull);
          if (lo){
            int colr = colB + (quad << 4) + (r << 2);
            int pre = __popc(lo & ((1 << l15) - 1));
            if (p[r]){
              unsigned pk = ((__float_as_uint(d2v[r]) + 0x2000u) & 0xFFFFC000u) | (unsigned)kidx;
              buf[(cntR[r] + pre) * CSTR + colr] = pk;
            }
            cntR[r] += __popc(lo);      // quad-uniform update, no atomics
          }
        }
      }
    }
  };

  auto check_compact = [&](int limit){
    #pragma unroll
    for (int r = 0; r < 4; r++){
      unsigned long long mr = __ballot(cntR[r] > limit);
      while (mr){
        int ldr = __ffsll((unsigned long long)mr) - 1;
        int qd = ldr >> 4;
        mr &= ~(0xFFFFull << (qd << 4));
        int col = colB + (qd << 4) + (r << 2);
        int cn = __shfl(cntR[r], qd << 4, 64);
        unsigned T = col_compact(buf, col, cn, lane);
        if (quad == qd) cntR[r] = 32;
        if (lane == 0) atomicMin(&tauG[(wq << 4) + (qd << 2) + r], T);
      }
    }
  };

  // ---- prologue: issue slots 0..3 (groups 0..3) ----
  #pragma unroll
  for (int u = 0; u < 4; u++){
    GLD0(sl[u][0], kcur); GLD64(sl[u][1], kcur); GLD128(sl[u][2], kcur);
    kcur += 3328;
  }

  // ---- main scan: 256 groups, steady 12 loads in flight, vmcnt(9) gates ----
  #pragma unroll 1
  for (int gb = 0; gb < 256; gb += 4){
    #pragma unroll
    for (int u = 0; u < 4; u++){
      int g = gb + u;
      WAITV(9);                                   // slot u (group g) landed
      __builtin_amdgcn_sched_barrier(0);          // MFMA may not hoist above
      float d2v[4];
      comp(sl[u], d2v);
      GLD0(sl[u][0], kcur); GLD64(sl[u][1], kcur); GLD128(sl[u][2], kcur);
      kcur += 3328;                               // prefetch group g+4
      if (g < 2) seed(d2v, g);
      else process(d2v, g);
      if (u & 1){
        check_compact(THRESH);
        uint4 tg = *(const uint4*)&tauG[(wq << 4) + (quad << 2)];
        tauR[0] = __uint_as_float(tg.x & 0xFFFFC000u);
        tauR[1] = __uint_as_float(tg.y & 0xFFFFC000u);
        tauR[2] = __uint_as_float(tg.z & 0xFFFFC000u);
        tauR[3] = __uint_as_float(tg.w & 0xFFFFC000u);
      }
    }
  }
  WAITV(0);                                       // drain overrun prefetches
  __builtin_amdgcn_sched_barrier(0);

  // ---- final per-column exact top-32 (all columns end at exactly 32) ----
  check_compact(32);
  __syncthreads();

  // ---- per-query merge of 4 columns (4x32 = 128 fixed) -> top-32 into mg ----
  #pragma unroll 1
  for (int s = 0; s < 4; s++){
    int q = (wv << 2) + s;           // 0..63
    unsigned e0 = buf[(lane & 31) * CSTR + (q << 2) + (lane >> 5)];
    unsigned e1 = buf[(lane & 31) * CSTR + (q << 2) + 2 + (lane >> 5)];
    unsigned T = 0;
    #pragma unroll 1
    for (int bb = 31; bb >= 0; --bb){
      unsigned cand = T | (1u << bb);
      int c = __popcll(__ballot(e0 < cand)) + __popcll(__ballot(e1 < cand));
      if (c <= 31) T = cand;
    }
    unsigned long long m0 = __ballot(e0 <= T);
    unsigned long long m1 = __ballot(e1 <= T);
    int b1 = __popcll(m0);
    unsigned long long ltm = (1ull << lane) - 1ull;
    int p0 = __popcll(m0 & ltm);
    int p1 = b1 + __popcll(m1 & ltm);
    if ((e0 <= T) && (p0 < 32)) mg[(q << 5) + p0] = e0;
    if ((e1 <= T) && (p1 < 32)) mg[(q << 5) + p1] = e1;
  }
  __syncthreads();

  // ---- fp64 exact rerank of 32 candidates/query (overlays buf region) ----
  double* qkf = (double*)(smem);
  double* rrD = (double*)(smem + 34304);
  int*    rrI = (int*)(smem + 50688);

  {
    int t16 = tid & 15, q = tid >> 4;
    int node = bbase + ((qloc0 + q) << 2);
    const float* xr = x + node * 64;
    for (int dd = t16; dd < 67; dd += 16){
      double val;
      if (dd < 16) val = (double)xr[dd];
      else if (dd < 64){
        int r = dd - 16; int k = r / 3; int a = r - 3 * k;
        val = (double)lfr[node*9 + a]     * (double)xr[16 + 3*k]
            + (double)lfr[node*9 + 3 + a] * (double)xr[17 + 3*k]
            + (double)lfr[node*9 + 6 + a] * (double)xr[18 + 3*k];
      } else val = (double)pos[node*3 + (dd - 64)];
      qkf[q * 67 + dd] = val;
    }
  }
  __syncthreads();
  {
    int t16 = tid & 15, q = tid >> 4;
    for (int j = t16; j < 32; j += 16){
      int idx = (int)(mg[(q << 5) + j] & 0x3FFFu);
      int node = bbase + idx;
      const float* xr = x + node * 64;
      double R[9];
      #pragma unroll
      for (int t = 0; t < 9; t++) R[t] = (double)lfr[node * 9 + t];
      double d2 = 0.0;
      #pragma unroll
      for (int dd = 0; dd < 16; dd++){ double t = (double)xr[dd] - qkf[q*67 + dd]; d2 += t * t; }
      #pragma unroll
      for (int k = 0; k < 16; k++){
        double v0 = xr[16 + 3*k], v1 = xr[17 + 3*k], v2 = xr[18 + 3*k];
        #pragma unroll
        for (int a = 0; a < 3; a++){
          double val = R[a] * v0 + R[3 + a] * v1 + R[6 + a] * v2;
          double t = val - qkf[q*67 + 16 + 3*k + a]; d2 += t * t;
        }
      }
      #pragma unroll
      for (int a = 0; a < 3; a++){ double t = (double)pos[node*3 + a] - qkf[q*67 + 64 + a]; d2 += t * t; }
      rrD[q * 32 + j] = d2; rrI[q * 32 + j] = idx;
    }
  }
  __syncthreads();
  if (tid < 64){
    int qq = tid;
    int qid = (b << 12) + qloc0 + qq;
    #pragma unroll 1
    for (int s = 0; s < KNN; s++){
      double best = rrD[qq * 32 + s]; int bi = s;
      for (int t = s + 1; t < 32; t++){
        double v = rrD[qq * 32 + t]; if (v < best){ best = v; bi = t; }
      }
      double tv = rrD[qq * 32 + bi]; rrD[qq * 32 + bi] = rrD[qq * 32 + s]; rrD[qq * 32 + s] = tv;
      int ti = rrI[qq * 32 + bi]; rrI[qq * 32 + bi] = rrI[qq * 32 + s]; rrI[qq * 32 + s] = ti;
      nbr[qid * KNN + s] = bbase + rrI[qq * 32 + s];
    }
  }
}

// ---------------------------------------------------------------------------
// k_mlp (MFMA rewrite): 8 queries/block = 160 edge-rows (10 m-tiles), 512 thr
// (8 waves, wave wv owns 16 output cols). bf16 MFMA both layers, fp32 acc.
// LDS k-blocked layouts [k/32][row][32] (16B-aligned b128 frags, 2-way banks).
// Max-over-20-edges fully in registers via compile-time query-boundary masks.
// ---------------------------------------------------------------------------
#define M_X   0         // xs f32[160][68] = 43520 ; later Wt2 bf16[4][128][32]
#define M_H   43520     // hB bf16[4][160][32] = 40960
#define M_A1  84480     // a1B bf16[4][160][32] = 40960 (early: nbrL/xdL/lfL overlay)
#define M_W   125440    // Wt1 bf16[4][128][32] = 32768
#define M_B1  158208    // b1 f32[128]
#define M_B2  158720    // b2 f32[128]
#define M_SZ  159232

__global__ __launch_bounds__(512) void k_mlp(const float* __restrict__ x,
    const float* __restrict__ lfr, const int* __restrict__ nbr,
    const float* __restrict__ W1, const float* __restrict__ b1,
    const float* __restrict__ W2, const float* __restrict__ b2,
    float* __restrict__ out){
  __shared__ __attribute__((aligned(16))) char smem[M_SZ];
  float* xsF = (float*)(smem + M_X);
  unsigned short* hB = (unsigned short*)(smem + M_H);
  unsigned short* a1B = (unsigned short*)(smem + M_A1);
  unsigned short* wt1 = (unsigned short*)(smem + M_W);
  unsigned short* wt2 = (unsigned short*)(smem + M_X);
  float* b1L = (float*)(smem + M_B1);
  float* b2L = (float*)(smem + M_B2);
  int*   nbrL = (int*)(smem + M_A1);            // overlay (dead before a1 writes)
  float* xdL  = (float*)(smem + M_A1 + 640);    // 8x64 f32
  float* lfL  = (float*)(smem + M_A1 + 2688);   // 8x9 f32

  int tid = threadIdx.x;
  int qid0 = blockIdx.x * 8;
  int lane = tid & 63, wv = tid >> 6;
  int l15 = lane & 15, quad = lane >> 4;

  // ---- init loads ----
  if (tid < 160) nbrL[tid] = nbr[qid0 * 20 + tid];
  {
    int q = tid >> 6, d = tid & 63;
    int qid = qid0 + q;
    int node = ((qid >> 12) << 14) + ((qid & 4095) << 2);
    xdL[q * 64 + d] = x[node * 64 + d];
  }
  if (tid < 72){
    int q = tid / 9, j = tid - 9 * q;
    int qid = qid0 + q;
    int node = ((qid >> 12) << 14) + ((qid & 4095) << 2);
    lfL[q * 9 + j] = lfr[node * 9 + j];
  }
  if (tid < 128){ b1L[tid] = b1[tid]; b2L[tid] = b2[tid]; }
  __syncthreads();

  // ---- gather x_src into xs (160 rows x 64 f32, stride 68) ----
  {
    int f4 = tid & 15;
    #pragma unroll
    for (int p = 0; p < 5; p++){
      int e = (tid >> 4) + (p << 5);
      float4 v = *(const float4*)&x[(size_t)nbrL[e] * 64 + (f4 << 2)];
      *(float4*)&xsF[e * 68 + (f4 << 2)] = v;
    }
  }
  __syncthreads();

  // ---- build h bf16 into hB [d>>5][e][d&31] ----
  {
    int d = tid & 127, eo = tid >> 7;   // eo 0..3
    int cls, kk = 0, aa = 0;
    if (d < 64) cls = 0;
    else { int dd = d - 64;
      if (dd < 16) cls = 1;
      else { cls = 2; int r = dd - 16; kk = (r * 21846) >> 16; aa = r - 3 * kk; } }
    int hoff = ((d >> 5) * 160) * 32 + (d & 31);
    #pragma unroll 4
    for (int p = 0; p < 40; p++){
      int e = eo + (p << 2);
      int q = (e * 3277) >> 16;       // e/20 for e<160
      float v;
      if (cls == 0) v = xdL[q * 64 + d];
      else if (cls == 1) v = xsF[e * 68 + (d - 64)] - xdL[q * 64 + (d - 64)];
      else {
        int base = 16 + 3 * kk;
        float u0 = xsF[e * 68 + base]     - xdL[q * 64 + base];
        float u1 = xsF[e * 68 + base + 1] - xdL[q * 64 + base + 1];
        float u2 = xsF[e * 68 + base + 2] - xdL[q * 64 + base + 2];
        v = lfL[q * 9 + aa * 3] * u0 + lfL[q * 9 + aa * 3 + 1] * u1 + lfL[q * 9 + aa * 3 + 2] * u2;
      }
      hB[hoff + e * 32] = f2bf_rne(v);
    }
  }
  __syncthreads();   // hB done; xs/xdL/lfL/nbrL dead

  // ---- stage Wt1 -> M_W, Wt2 -> M_X  (layout [k>>5][n][32], value W[k][n]) ----
  #pragma unroll 4
  for (int i = tid; i < 16384; i += 512){
    int k = i >> 7, n = i & 127;
    int a = ((k >> 5) * 128 + n) * 32 + (k & 31);
    wt1[a] = f2bf_rne(W1[i]);
    wt2[a] = f2bf_rne(W2[i]);
  }
  __syncthreads();   // weights visible

  // ---- layer 1: a1 = relu(h @ W1 + b1) ----
  {
    s16x8 bfr[4];
    #pragma unroll
    for (int ks = 0; ks < 4; ks++)
      bfr[ks] = *(const s16x8*)(wt1 + ((ks * 128 + (wv << 4) + l15) * 32 + (quad << 3)));
    float b1v = b1L[(wv << 4) + l15];
    int colhi = wv >> 1, collo = ((wv & 1) << 4) + l15;
    #pragma unroll
    for (int mt = 0; mt < 10; mt++){
      f32x4 acc = (f32x4){0.f, 0.f, 0.f, 0.f};
      #pragma unroll
      for (int ks = 0; ks < 4; ks++){
        s16x8 af = *(const s16x8*)(hB + ((ks * 160 + (mt << 4) + l15) * 32 + (quad << 3)));
        acc = __builtin_amdgcn_mfma_f32_16x16x32_bf16(af, bfr[ks], acc, 0, 0, 0);
      }
      #pragma unroll
      for (int r = 0; r < 4; r++){
        float v = fmaxf(acc[r] + b1v, 0.f);
        int row = (mt << 4) + (quad << 2) + r;
        a1B[(colhi * 160 + row) * 32 + collo] = f2bf_rne(v);
      }
    }
  }
  __syncthreads();   // a1 complete

  // ---- layer 2 + max over edges (registers only) ----
  {
    s16x8 bfr[4];
    #pragma unroll
    for (int ks = 0; ks < 4; ks++)
      bfr[ks] = *(const s16x8*)(wt2 + ((ks * 128 + (wv << 4) + l15) * 32 + (quad << 3)));
    float mxv[8];
    #pragma unroll
    for (int q = 0; q < 8; q++) mxv[q] = -3.0e38f;
    const int QA[10]  = {0,0,1,2,3,4,4,5,6,7};
    const int CUT[10] = {16,4,8,12,16,16,4,8,12,16};
    #pragma unroll
    for (int mt = 0; mt < 10; mt++){
      f32x4 acc = (f32x4){0.f, 0.f, 0.f, 0.f};
      #pragma unroll
      for (int ks = 0; ks < 4; ks++){
        s16x8 af = *(const s16x8*)(a1B + ((ks * 160 + (mt << 4) + l15) * 32 + (quad << 3)));
        acc = __builtin_amdgcn_mfma_f32_16x16x32_bf16(af, bfr[ks], acc, 0, 0, 0);
      }
      int qa = QA[mt], cut = CUT[mt];
      if (cut >= 16){
        #pragma unroll
        for (int r = 0; r < 4; r++) mxv[qa] = fmaxf(mxv[qa], acc[r]);
      } else {
        #pragma unroll
        for (int r = 0; r < 4; r++){
          int lr = (quad << 2) + r;
          bool toA = lr < cut;
          mxv[qa]     = fmaxf(mxv[qa],     toA ? acc[r] : -3.0e38f);
          mxv[qa + 1] = fmaxf(mxv[qa + 1], toA ? -3.0e38f : acc[r]);
        }
      }
    }
    // combine across quads (rows) -- all lanes end with full per-col max
    #pragma unroll
    for (int q = 0; q < 8; q++){
      float v = mxv[q];
      v = fmaxf(v, __shfl_xor(v, 16, 64));
      v = fmaxf(v, __shfl_xor(v, 32, 64));
      mxv[q] = v;
    }
    if (quad == 0){
      int col = (wv << 4) + l15;
      float b2v = b2L[col];
      #pragma unroll
      for (int q = 0; q < 8; q++)
        out[(size_t)(qid0 + q) * 128 + col] = mxv[q] + b2v;
    }
  }
}

// ---------------------------------------------------------------------------
// k_tail: pos[idx], batch[idx], lframes[idx] as fp32 at flat offsets.
// ---------------------------------------------------------------------------
__global__ __launch_bounds__(256) void k_tail(const float* __restrict__ pos,
    const float* __restrict__ lfr, float* __restrict__ out){
  int q = blockIdx.x * 256 + threadIdx.x;   // 0..16383
  int b = q >> 12;
  int node = (b << 14) + ((q & 4095) << 2);
  float* o_pos = out + 2097152;    // 16384*128
  float* o_bat = out + 2146304;    // + 16384*3
  float* o_lf  = out + 2162688;    // + 16384
  #pragma unroll
  for (int j = 0; j < 3; j++) o_pos[q * 3 + j] = pos[node * 3 + j];
  o_bat[q] = (float)b;
  #pragma unroll
  for (int j = 0; j < 9; j++) o_lf[q * 9 + j] = lfr[node * 9 + j];
}

extern "C" void kernel_launch(void* const* d_in, const int* in_sizes, int n_in,
                              void* d_out, int out_size, void* d_ws, size_t ws_size,
                              hipStream_t stream){
  const float* x   = (const float*)d_in[0];
  const float* pos = (const float*)d_in[1];
  const float* lfr = (const float*)d_in[2];
  // d_in[3] = batch (recomputed analytically)
  const float* W1  = (const float*)d_in[4];
  const float* b1  = (const float*)d_in[5];
  const float* W2  = (const float*)d_in[6];
  const float* b2  = (const float*)d_in[7];

  unsigned short* kfB = (unsigned short*)d_ws;
  float* normB = (float*)((char*)d_ws + WS_NORM);
  int*   nbr   = (int*)((char*)d_ws + WS_NBR);
  float* out = (float*)d_out;

  hipLaunchKernelGGL(k_prep, dim3(256),  dim3(256),  0, stream, x, pos, lfr, kfB, normB);
  hipLaunchKernelGGL(k_knn,  dim3(256),  dim3(1024), 0, stream, kfB, normB, x, pos, lfr, nbr);
  hipLaunchKernelGGL(k_mlp,  dim3(2048), dim3(512),  0, stream, x, lfr, nbr, W1, b1, W2, b2, out);
  hipLaunchKernelGGL(k_tail, dim3(64),   dim3(256),  0, stream, pos, lfr, out);
}